// Round 13
// baseline (859.038 us; speedup 1.0000x reference)
//
#include <hip/hip_runtime.h>
#include <math.h>

// ---------------- problem constants ----------------
constexpr int kH = 48, kW = 64, kHW = 3072, kC = 256;
constexpr int kHidden = 128, kCtx = 64;
constexpr int kP = 81, kCorrDim = 324;  // 81*4
constexpr int kNS = 37, kIters = 4;
constexpr int kGin = kHidden + kCorrDim + kCtx;  // 516
// padded spatial domain for conv inputs
constexpr int kWp2 = 66, kHp2 = 50, kPix = 3300;  // (48+2)x(64+2)
constexpr int kCF = 416;   // fused(324)+ctx(64)+pad(28) = 13*32
constexpr int kCHh = 128;  // h / rh channels = 4*32

// box-filtered pyramid (padded +10 each dim), per source pixel
constexpr int kSB0 = 0, kSB1 = 4292, kSB2 = 5720, kSB3 = 6292, kSBTot = 6580;
constexpr int kHB0 = 0, kHB1 = 3552, kHB2 = 4560, kHB3 = 4872, kHBTot = 4980;

// ---------------- workspace layout ----------------
constexpr size_t U_CORR0 = 0;
constexpr size_t U_CORR1 = U_CORR0 + (size_t)kHW * 3072;
constexpr size_t U_CORR2 = U_CORR1 + (size_t)kHW * 768;
constexpr size_t U_CORR3 = U_CORR2 + (size_t)kHW * 192;
constexpr size_t U_END0  = U_CORR3 + (size_t)kHW * 48;
constexpr size_t F_X     = U_END0 / 2;
constexpr size_t F_H     = F_X + (size_t)kHW * 3;
constexpr size_t F_ZPRE  = F_H + (size_t)kHidden * kHW;
constexpr size_t F_END1  = F_ZPRE + (size_t)kHidden * kHW;
constexpr size_t U_FCT   = F_END1 * 2;                    // 3300*416
constexpr size_t U_HT    = U_FCT + (size_t)kPix * kCF;    // 3300*128
constexpr size_t U_RHT   = U_HT + (size_t)kPix * kCHh;    // 3300*128
constexpr size_t U_PZR   = U_RHT + (size_t)kPix * kCHh;
constexpr size_t U_PQ    = U_PZR + (size_t)16 * 9 * 17 * 512;
constexpr size_t U_PH    = U_PQ + (size_t)8 * 9 * 17 * 512;
constexpr size_t U_END2  = U_PH + (size_t)8 * 9 * 4 * 512;
constexpr size_t F_BZR   = U_END2 / 2 + 1;
constexpr size_t F_CONF  = F_BZR + 256;
constexpr size_t F_POSE  = F_CONF + 64;
constexpr size_t F_FEAT  = F_POSE + 16;
constexpr size_t F_SAMP  = F_FEAT + 128;   // 37*12
constexpr size_t F_CNT   = F_SAMP + 448;   // completion counter
constexpr size_t F_END3  = F_CNT + 16;
constexpr size_t U_FDT   = F_END3 * 2;
constexpr size_t U_QT    = U_FDT + (size_t)kHW * kC;
constexpr size_t U_SBOX  = U_FDT;  // overlays fdT/qT after setup

typedef __attribute__((ext_vector_type(8))) short short8;
typedef __attribute__((ext_vector_type(4))) float f32x4;

__device__ inline unsigned short f2b(float f) {
  unsigned int u = __float_as_uint(f);
  unsigned int r = u + 0x7FFF + ((u >> 16) & 1);
  return (unsigned short)(r >> 16);
}
__device__ inline float b2f(unsigned short u) {
  return __uint_as_float(((unsigned int)u) << 16);
}
__device__ inline int clampi(int v, int lo, int hi) { return min(max(v, lo), hi); }

// ---------------- sample templates ----------------
__constant__ float c_rot[12][3] = {
  {0,0,0},{0,0,0},{0,0,0},{0,0,0},{0,0,0},{0,0,0},
  {1,0,0},{-1,0,0},{0,1,0},{0,-1,0},{0,0,1},{0,0,-1}};
__constant__ float c_trs[12][3] = {
  {1,0,0},{-1,0,0},{0,1,0},{0,-1,0},{0,0,1},{0,0,-1},
  {0,0,0},{0,0,0},{0,0,0},{0,0,0},{0,0,0},{0,0,0}};

// ---------------- device helpers ----------------
__device__ inline void d_qmul(const float* q, const float* r, float* o) {
  o[0] = q[0]*r[0] - q[1]*r[1] - q[2]*r[2] - q[3]*r[3];
  o[1] = q[0]*r[1] + q[1]*r[0] + q[2]*r[3] - q[3]*r[2];
  o[2] = q[0]*r[2] - q[1]*r[3] + q[2]*r[0] + q[3]*r[1];
  o[3] = q[0]*r[3] + q[1]*r[2] - q[2]*r[1] + q[3]*r[0];
}
__device__ inline void d_qapply(const float* q, const float* v, float* o) {
  float a0 = -q[1]*v[0] - q[2]*v[1] - q[3]*v[2];
  float a1 =  q[0]*v[0] + q[2]*v[2] - q[3]*v[1];
  float a2 =  q[0]*v[1] - q[1]*v[2] + q[3]*v[0];
  float a3 =  q[0]*v[2] + q[1]*v[1] - q[2]*v[0];
  o[0] = -a0*q[1] + a1*q[0] - a2*q[3] + a3*q[2];
  o[1] = -a0*q[2] + a1*q[3] + a2*q[0] - a3*q[1];
  o[2] = -a0*q[3] - a1*q[2] + a2*q[1] + a3*q[0];
}
__device__ inline void d_intr(const float* intr, float& fx, float& fy, float& cx, float& cy) {
  fx = 60.f + 40.f*intr[0];
  fy = 60.f + 40.f*intr[1];
  cx = 32.f + 4.f*(intr[2] - 0.5f);
  cy = 24.f + 4.f*(intr[3] - 0.5f);
}
__device__ inline void sample_Rt(int t, const float* __restrict__ pose, float* S) {
  float qc[4] = {pose[0], pose[1], pose[2], pose[3]};
  float tc[3] = {pose[4], pose[5], pose[6]};
  float dq[4], dt[3];
  if (t == 36) {
    dq[0] = 1.f; dq[1] = dq[2] = dq[3] = 0.f;
    dt[0] = dt[1] = dt[2] = 0.f;
  } else {
    int j = t / 3, k = t % 3;
    float sc = (k == 0) ? 0.25f : ((k == 1) ? 1.f : 4.f);
    float rx = c_rot[j][0], ry = c_rot[j][1], rz = c_rot[j][2];
    float nrm = sqrtf(rx*rx + ry*ry + rz*rz);
    float axn = fmaxf(nrm, 1e-8f);
    float ax = rx / axn, ay = ry / axn, az = rz / axn;
    float ha = 0.02f * sc * 0.5f;
    float sh = sinf(ha), ch = cosf(ha);
    dq[0] = ch; dq[1] = ax * sh; dq[2] = ay * sh; dq[3] = az * sh;
    dt[0] = c_trs[j][0] * (0.02f * sc);
    dt[1] = c_trs[j][1] * (0.02f * sc);
    dt[2] = c_trs[j][2] * (0.02f * sc);
  }
  float qn[4];
  d_qmul(qc, dq, qn);
  float inv = 1.f / sqrtf(qn[0]*qn[0] + qn[1]*qn[1] + qn[2]*qn[2] + qn[3]*qn[3]);
  qn[0] *= inv; qn[1] *= inv; qn[2] *= inv; qn[3] *= inv;
  float tr[3];
  d_qapply(qc, dt, tr);
  float w = qn[0], x = qn[1], y = qn[2], z = qn[3];
  S[0] = 1.f - 2.f*(y*y + z*z); S[1] = 2.f*(x*y - w*z);       S[2] = 2.f*(x*z + w*y);
  S[3] = 2.f*(x*y + w*z);       S[4] = 1.f - 2.f*(x*x + z*z); S[5] = 2.f*(y*z - w*x);
  S[6] = 2.f*(x*z - w*y);       S[7] = 2.f*(y*z + w*x);       S[8] = 1.f - 2.f*(x*x + y*y);
  S[9]  = tc[0] + tr[0];
  S[10] = tc[1] + tr[1];
  S[11] = tc[2] + tr[2];
}
__device__ inline void project_uv(const float* S, const float* Xp, const float* intr,
                                  float& u, float& v) {
  float xc0 = S[0]*Xp[0] + S[1]*Xp[1] + S[2]*Xp[2] + S[9];
  float xc1 = S[3]*Xp[0] + S[4]*Xp[1] + S[5]*Xp[2] + S[10];
  float xc2 = S[6]*Xp[0] + S[7]*Xp[1] + S[8]*Xp[2] + S[11];
  float z = fmaxf(xc2, 0.1f);
  float fx, fy, cx, cy;
  d_intr(intr, fx, fy, cx, cy);
  u = fx * xc0 / z + cx;
  v = fy * xc1 / z + cy;
}

// ---------------- init (merged); precomputes samp for identity pose; zeroes cnt ----------------
__global__ void init_k(const float* __restrict__ ctx, const float* __restrict__ bz,
                       const float* __restrict__ br, const float* __restrict__ depth,
                       const float* __restrict__ intr, float* __restrict__ h,
                       unsigned int* __restrict__ zbase, unsigned short* __restrict__ fcT,
                       float* __restrict__ bzr, float* __restrict__ X,
                       float* __restrict__ conf, float* __restrict__ feat,
                       float* __restrict__ pose, float* __restrict__ samp,
                       unsigned int* __restrict__ cnt) {
  const size_t nz = ((size_t)kPix * (kCF + 2 * kCHh)) / 2;  // uint count
  for (size_t i = blockIdx.x * blockDim.x + threadIdx.x; i < nz;
       i += (size_t)gridDim.x * blockDim.x)
    zbase[i] = 0;
  int idx = blockIdx.x * blockDim.x + threadIdx.x;
  if (idx < kHidden * kHW) h[idx] = 0.f;
  if (idx < kHW) {
    float fx, fy, cx, cy;
    d_intr(intr, fx, fy, cx, cy);
    float d = 4.f + 20.f * depth[idx];
    float u = (float)(idx % kW), v = (float)(idx / kW);
    X[idx*3+0] = (u - cx) / fx * d;
    X[idx*3+1] = (v - cy) / fy * d;
    X[idx*3+2] = d;
  }
  if (idx < 256) bzr[idx] = (idx < 128) ? bz[idx] : br[idx - 128];
  if (idx < 64) conf[idx] = 0.f;
  if (idx < 128) feat[idx] = 0.f;
  if (idx < kNS) {
    const float ipose[7] = {1.f, 0.f, 0.f, 0.f, 0.f, 0.f, 0.f};
    sample_Rt(idx, ipose, samp + idx * 12);
  }
  if (idx == 0) {
    pose[0] = 1.f;
    for (int j = 1; j < 7; ++j) pose[j] = 0.f;
    *cnt = 0;
  }
}

// ---------------- merged setup: ctx copy + all 3 weight packs ----------------
__device__ inline void pack_one(const float* __restrict__ W0, const float* __restrict__ W1,
                                int ocSplit, int NCH, int Cin,
                                unsigned short* __restrict__ P, int idx) {
  int g = idx & 3;
  int m = (idx >> 2) & 15;
  int rest = idx >> 6;
  int cc = rest % NCH;
  int rest2 = rest / NCH;
  int tap = rest2 % 9;
  int ot = rest2 / 9;
  int oc = ot * 16 + m;
  union { unsigned short u[8]; uint4 q; } v;
#pragma unroll
  for (int j = 0; j < 8; ++j) {
    int ci = cc * 32 + g * 8 + j;
    float w = 0.f;
    if (ci < Cin)
      w = (oc < ocSplit) ? W0[((size_t)oc * Cin + ci) * 9 + tap]
                         : W1[((size_t)(oc - ocSplit) * Cin + ci) * 9 + tap];
    v.u[j] = f2b(w);
  }
  *(uint4*)&P[(size_t)idx * 8] = v.q;
}

__global__ void setup2_k(const float* __restrict__ ctx, unsigned short* __restrict__ fcT,
                         const float* __restrict__ Wz, const float* __restrict__ Wr,
                         const float* __restrict__ Wq, const float* __restrict__ Wh,
                         unsigned short* __restrict__ Pzr, unsigned short* __restrict__ Pq,
                         unsigned short* __restrict__ Ph) {
  int idx = blockIdx.x * blockDim.x + threadIdx.x;
  if (idx < 196608) {  // ctx -> fcT interior (after init zeroing)
    int p = idx >> 6, c = idx & 63;
    int ppix = ((p >> 6) + 1) * kWp2 + (p & 63) + 1;
    fcT[(size_t)ppix * kCF + kCorrDim + c] = f2b(ctx[(size_t)c * kHW + p]);
  } else if (idx < 353280) {
    pack_one(Wz, Wr, 128, 17, kGin, Pzr, idx - 196608);
  } else if (idx < 431616) {
    pack_one(Wq, Wq, 128, 17, kGin, Pq, idx - 353280);
  } else if (idx < 450048) {
    pack_one(Wh, Wh, 128, 4, kHidden, Ph, idx - 431616);
  }
}

// ---------------- fp32 [C][HW] -> bf16 [HW][C] transpose (both maps, one launch) ----------------
__global__ __launch_bounds__(256) void t_bf16_k(const float* __restrict__ fdep,
                                                const float* __restrict__ frgb,
                                                unsigned short* __restrict__ fdT,
                                                unsigned short* __restrict__ qT) {
  __shared__ float t[64][65];
  const int tid = threadIdx.x;
  const int which = blockIdx.y >> 2;
  const float* src = which ? frgb : fdep;
  unsigned short* dst = which ? qT : fdT;
  const int p0 = blockIdx.x * 64, c0 = (blockIdx.y & 3) * 64;
  const int tx = tid & 63, ty = tid >> 6;
  for (int cl = ty; cl < 64; cl += 4)
    t[cl][tx] = src[(size_t)(c0 + cl) * kHW + p0 + tx];
  __syncthreads();
  for (int pl = ty; pl < 64; pl += 4)
    dst[(size_t)(p0 + pl) * kC + c0 + tx] = f2b(t[tx][pl]);
}

// ---------------- corr GEMM via MFMA -> bf16 pyramid L0 ----------------
__global__ __launch_bounds__(256) void corr_mfma_k(const unsigned short* __restrict__ fdT,
                                                   const unsigned short* __restrict__ qT,
                                                   unsigned short* __restrict__ Cg) {
  const int tid = threadIdx.x;
  const int wv = tid >> 6, lane = tid & 63;
  const int m = lane & 15, kg = lane >> 4;
  const int i0 = blockIdx.y * 128 + wv * 32;
  const int q0 = blockIdx.x * 128;

  f32x4 acc[2][8];
#pragma unroll
  for (int t = 0; t < 2; ++t)
#pragma unroll
    for (int u = 0; u < 8; ++u) acc[t][u] = (f32x4){0.f, 0.f, 0.f, 0.f};

#pragma unroll
  for (int kc = 0; kc < 8; ++kc) {
    const int kb = kc * 32 + kg * 8;
    short8 a[2], b[8];
#pragma unroll
    for (int t = 0; t < 2; ++t)
      a[t] = *(const short8*)&fdT[(size_t)(i0 + t * 16 + m) * kC + kb];
#pragma unroll
    for (int u = 0; u < 8; ++u)
      b[u] = *(const short8*)&qT[(size_t)(q0 + u * 16 + m) * kC + kb];
#pragma unroll
    for (int t = 0; t < 2; ++t)
#pragma unroll
      for (int u = 0; u < 8; ++u)
        acc[t][u] = __builtin_amdgcn_mfma_f32_16x16x32_bf16(a[t], b[u], acc[t][u], 0, 0, 0);
  }
  const float S = 0.0625f;
#pragma unroll
  for (int t = 0; t < 2; ++t)
#pragma unroll
    for (int u = 0; u < 8; ++u)
#pragma unroll
      for (int r = 0; r < 4; ++r)
        Cg[(size_t)(i0 + t * 16 + kg * 4 + r) * kHW + q0 + u * 16 + m] = f2b(acc[t][u][r] * S);
}

// ---------------- box-filter build + pyramid pooling, one block per source pixel ----------------
template<int HL>
__device__ inline void colpref(float* base, int Wp) {
  float v[HL];
#pragma unroll
  for (int y = 0; y < HL; ++y) v[y] = base[(size_t)y * Wp];
  float run = 0.f;
#pragma unroll
  for (int y = 0; y < HL; ++y) {
    run += v[y];
    base[(size_t)y * Wp] = run;
  }
}

__global__ __launch_bounds__(256) void boxbuild_k(const unsigned short* __restrict__ corr0,
                                                  unsigned short* __restrict__ corr1,
                                                  unsigned short* __restrict__ corr2,
                                                  unsigned short* __restrict__ corr3,
                                                  unsigned short* __restrict__ Sbox) {
  __shared__ float pyr[4080];
  __shared__ float hb[kHBTot];
  const int i = blockIdx.x;
  const int tid = threadIdx.x;
  const int wv = tid >> 6, lane = tid & 63;

  for (int idx = tid; idx < 3072; idx += 256)
    pyr[idx] = b2f(corr0[(size_t)i * 3072 + idx]);
  __syncthreads();

  for (int c = tid; c < 768; c += 256) {
    int y = c >> 5, x = c & 31;
    float v = 0.25f * (pyr[(2*y)*64 + 2*x] + pyr[(2*y)*64 + 2*x + 1] +
                       pyr[(2*y+1)*64 + 2*x] + pyr[(2*y+1)*64 + 2*x + 1]);
    unsigned short b = f2b(v);
    corr1[(size_t)i * 768 + c] = b;
    pyr[3072 + c] = b2f(b);
  }
  __syncthreads();
  for (int c = tid; c < 192; c += 256) {
    int y = c >> 4, x = c & 15;
    const float* p = pyr + 3072;
    float v = 0.25f * (p[(2*y)*32 + 2*x] + p[(2*y)*32 + 2*x + 1] +
                       p[(2*y+1)*32 + 2*x] + p[(2*y+1)*32 + 2*x + 1]);
    unsigned short b = f2b(v);
    corr2[(size_t)i * 192 + c] = b;
    pyr[3840 + c] = b2f(b);
  }
  __syncthreads();
  for (int c = tid; c < 48; c += 256) {
    int y = c >> 3, x = c & 7;
    const float* p = pyr + 3840;
    float v = 0.25f * (p[(2*y)*16 + 2*x] + p[(2*y)*16 + 2*x + 1] +
                       p[(2*y+1)*16 + 2*x] + p[(2*y+1)*16 + 2*x + 1]);
    unsigned short b = f2b(v);
    corr3[(size_t)i * 48 + c] = b;
    pyr[4032 + c] = b2f(b);
  }
  __syncthreads();

  const int lvl_off[4] = {0, 3072, 3840, 4032};
  for (int r = wv; r < 90; r += 4) {
    int lvl, y;
    if (r < 48)      { lvl = 0; y = r; }
    else if (r < 72) { lvl = 1; y = r - 48; }
    else if (r < 84) { lvl = 2; y = r - 72; }
    else             { lvl = 3; y = r - 84; }
    const int Wl = kW >> lvl;
    float* row = &pyr[lvl_off[lvl] + y * Wl];
    float v = (lane < Wl) ? row[lane] : 0.f;
#pragma unroll
    for (int o = 1; o < 64; o <<= 1) {
      float tv = __shfl_up(v, o, 64);
      if (lane >= o) v += tv;
    }
    if (lane < Wl) row[lane] = v;
  }
  __syncthreads();

  for (int c = tid; c < 3552; c += 256) {
    int y = c / 74, as = c % 74;
    const float* pref = &pyr[y * 64];
    float Hv = 0.f;
    if (as >= 1) Hv = pref[min(63, as - 1)];
    if (as >= 10) Hv -= pref[as - 10];
    hb[kHB0 + c] = Hv;
  }
  for (int c = tid; c < 1008; c += 256) {
    int y = c / 42, as = c % 42;
    const float* pref = &pyr[3072 + y * 32];
    float Hv = 0.f;
    if (as >= 1) Hv = pref[min(31, as - 1)];
    if (as >= 10) Hv -= pref[as - 10];
    hb[kHB1 + c] = Hv;
  }
  for (int c = tid; c < 312; c += 256) {
    int y = c / 26, as = c % 26;
    const float* pref = &pyr[3840 + y * 16];
    float Hv = 0.f;
    if (as >= 1) Hv = pref[min(15, as - 1)];
    if (as >= 10) Hv -= pref[as - 10];
    hb[kHB2 + c] = Hv;
  }
  for (int c = tid; c < 108; c += 256) {
    int y = c / 18, as = c % 18;
    const float* pref = &pyr[4032 + y * 8];
    float Hv = 0.f;
    if (as >= 1) Hv = pref[min(7, as - 1)];
    if (as >= 10) Hv -= pref[as - 10];
    hb[kHB3 + c] = Hv;
  }
  __syncthreads();

  if (tid < 160) {
    if (tid < 74)       colpref<48>(hb + kHB0 + tid, 74);
    else if (tid < 116) colpref<24>(hb + kHB1 + (tid - 74), 42);
    else if (tid < 142) colpref<12>(hb + kHB2 + (tid - 116), 26);
    else                colpref<6>(hb + kHB3 + (tid - 142), 18);
  }
  __syncthreads();

  unsigned short* out = Sbox + (size_t)i * kSBTot;
  for (int c = tid; c < 4292; c += 256) {
    int bp = c / 74, as = c % 74;
    const float* col = &hb[kHB0 + as];
    float S = 0.f;
    if (bp >= 1) S = col[min(47, bp - 1) * 74];
    if (bp >= 10) S -= col[(bp - 10) * 74];
    out[kSB0 + c] = f2b(S);
  }
  for (int c = tid; c < 1428; c += 256) {
    int bp = c / 42, as = c % 42;
    const float* col = &hb[kHB1 + as];
    float S = 0.f;
    if (bp >= 1) S = col[min(23, bp - 1) * 42];
    if (bp >= 10) S -= col[(bp - 10) * 42];
    out[kSB1 + c] = f2b(S);
  }
  for (int c = tid; c < 572; c += 256) {
    int bp = c / 26, as = c % 26;
    const float* col = &hb[kHB2 + as];
    float S = 0.f;
    if (bp >= 1) S = col[min(11, bp - 1) * 26];
    if (bp >= 10) S -= col[(bp - 10) * 26];
    out[kSB2 + c] = f2b(S);
  }
  for (int c = tid; c < 288; c += 256) {
    int bp = c / 18, as = c % 18;
    const float* col = &hb[kHB3 + as];
    float S = 0.f;
    if (bp >= 1) S = col[min(5, bp - 1) * 18];
    if (bp >= 10) S -= col[(bp - 10) * 18];
    out[kSB3 + c] = f2b(S);
  }
}

// ---------------- conf: one thread per (sample, pixel); 16 Sbox reads ----------------
__global__ __launch_bounds__(256) void conf_k(const unsigned short* __restrict__ Sbox,
                                              const float* __restrict__ X,
                                              const float* __restrict__ samp,
                                              const float* __restrict__ intr,
                                              float* __restrict__ conf) {
  const int idx = blockIdx.x * 256 + threadIdx.x;
  const int n = idx / kHW, i = idx - n * kHW;
  const float* S = samp + n * 12;
  float Xp[3] = {X[i*3], X[i*3+1], X[i*3+2]};
  float u, v;
  project_uv(S, Xp, intr, u, v);
  const unsigned short* sb = Sbox + (size_t)i * kSBTot;
  float tot = 0.f;
#pragma unroll
  for (int l = 0; l < 4; ++l) {
    const int Wp = (kW >> l) + 10, Hp = (kH >> l) + 10;
    const int so = (l == 0) ? kSB0 : (l == 1) ? kSB1 : (l == 2) ? kSB2 : kSB3;
    const float s = (float)(1 << l);
    const float bx = u / s, by = v / s;
    const float fbx = floorf(bx), fby = floorf(by);
    const int x0 = (int)fbx, y0 = (int)fby;
    const float fx = bx - fbx, fy = by - fby;
    const int xa = clampi(x0 + 5, 0, Wp - 1), xb = clampi(x0 + 6, 0, Wp - 1);
    const int ya = clampi(y0 + 5, 0, Hp - 1), yb = clampi(y0 + 6, 0, Hp - 1);
    const float s00 = b2f(sb[so + ya * Wp + xa]), s10 = b2f(sb[so + ya * Wp + xb]);
    const float s01 = b2f(sb[so + yb * Wp + xa]), s11 = b2f(sb[so + yb * Wp + xb]);
    tot += (1.f - fx) * (1.f - fy) * s00 + fx * (1.f - fy) * s10 +
           (1.f - fx) * fy * s01 + fx * fy * s11;
  }
#pragma unroll
  for (int o = 32; o; o >>= 1) tot += __shfl_xor(tot, o, 64);
  if ((threadIdx.x & 63) == 0) atomicAdd(&conf[n], tot);
}

// ---------------- fused corr features (inline top-k) -> fcT interior ----------------
__global__ __launch_bounds__(256) void fused_k(const unsigned short* __restrict__ corr0,
                                               const unsigned short* __restrict__ corr1,
                                               const unsigned short* __restrict__ corr2,
                                               const unsigned short* __restrict__ corr3,
                                               const float* __restrict__ X,
                                               const float* __restrict__ samp,
                                               const float* __restrict__ intr,
                                               const float* __restrict__ conf,
                                               unsigned short* __restrict__ fcT) {
  __shared__ float win[12][10][12];
  __shared__ float s_fx[12], s_fy[12];
  __shared__ int   s_ix[12], s_iy[12];
  __shared__ float s_w[3];
  __shared__ int   s_id[3];
  const int i = blockIdx.x;
  const int tid = threadIdx.x;

  if (tid == 0) {
    const float scale = 1.f / ((float)kHW * (float)kCorrDim);
    float c[kNS];
    for (int n = 0; n < kNS; ++n) c[n] = conf[n] * scale;
    int id[3] = {-1, -1, -1};
    float v[3];
    for (int k = 0; k < 3; ++k) {
      float best = -1e30f;
      int bi = -1;
      for (int n = 0; n < kNS; ++n) {
        if (n == id[0] || n == id[1] || n == id[2]) continue;
        if (c[n] > best) { best = c[n]; bi = n; }
      }
      v[k] = best;
      id[k] = bi;
    }
    float m = v[0];
    float e0 = expf(v[0] - m), e1 = expf(v[1] - m), e2 = expf(v[2] - m);
    float s = e0 + e1 + e2;
    s_w[0] = e0 / s; s_w[1] = e1 / s; s_w[2] = e2 / s;
    s_id[0] = id[0]; s_id[1] = id[1]; s_id[2] = id[2];
  }
  __syncthreads();

  if (tid < 3) {
    const float* S = samp + s_id[tid] * 12;
    float Xp[3] = {X[i*3], X[i*3+1], X[i*3+2]};
    float u, v;
    project_uv(S, Xp, intr, u, v);
#pragma unroll
    for (int l = 0; l < 4; ++l) {
      float s = (float)(1 << l);
      float bx = u / s, by = v / s;
      float fbx = floorf(bx), fby = floorf(by);
      s_ix[tid*4 + l] = (int)fbx;
      s_iy[tid*4 + l] = (int)fby;
      s_fx[tid*4 + l] = bx - fbx;
      s_fy[tid*4 + l] = by - fby;
    }
  }
  __syncthreads();

  for (int sidx = tid; sidx < 1200; sidx += 256) {
    const int w = sidx / 100, rem = sidx % 100;
    const int rr = rem / 10, cc = rem % 10;
    const int lvl = w & 3;
    const int Wl = kW >> lvl, Hl = kH >> lvl;
    const unsigned short* base =
        (lvl == 0) ? corr0 : (lvl == 1) ? corr1 : (lvl == 2) ? corr2 : corr3;
    const int y = s_iy[w] - 4 + rr;
    const int x = s_ix[w] - 4 + cc;
    float v = 0.f;
    if (y >= 0 && y < Hl && x >= 0 && x < Wl)
      v = b2f(base[(size_t)i * (Hl * Wl) + y * Wl + x]);
    win[w][rr][cc] = v;
  }
  __syncthreads();

  const int ppix = ((i >> 6) + 1) * kWp2 + (i & 63) + 1;
  for (int d = tid; d < kCorrDim; d += 256) {
    const int lvl = d / kP;
    const int o = d % kP;
    const int oyi = o / 9, oxi = o % 9;
    float val = 0.f;
#pragma unroll
    for (int k = 0; k < 3; ++k) {
      const int w = k * 4 + lvl;
      const float fx = s_fx[w], fy = s_fy[w];
      const float w00 = (1.f - fx) * (1.f - fy), w10 = fx * (1.f - fy);
      const float w01 = (1.f - fx) * fy, w11 = fx * fy;
      val += s_w[k] * (w00 * win[w][oyi][oxi] + w10 * win[w][oyi][oxi + 1] +
                       w01 * win[w][oyi + 1][oxi] + w11 * win[w][oyi + 1][oxi + 1]);
    }
    fcT[(size_t)ppix * kCF + d] = f2b(val);
  }
}

// ---------------- LDS-free maskless conv core: wave = 16 oc x 32 px, cc range ----------------
template<int CCB, int CCE, int NCHH, int NCHTOT>
__device__ inline void conv_core32(const unsigned short* __restrict__ srcH,
                                   const unsigned short* __restrict__ srcF,
                                   const unsigned short* __restrict__ A,
                                   int y, int xbase, int ot, int lane,
                                   f32x4 (&acc)[2]) {
  const int m = lane & 15, kg = lane >> 4;
  const unsigned short* a_base = A + (size_t)ot * (9 * NCHTOT * 512) + m * 32 + kg * 8;
  const int pix0 = (y + 1) * kWp2 + (xbase + 1) + m;
#pragma unroll
  for (int tap = 0; tap < 9; ++tap) {
    const int dy = tap / 3 - 1, dx = tap % 3 - 1;
    const int po = pix0 + dy * kWp2 + dx;
    const unsigned short* bh0 = srcH + (size_t)po * kCHh + kg * 8;
    const unsigned short* bf0 = srcF + (size_t)po * kCF + kg * 8;
#pragma unroll
    for (int cc = CCB; cc < CCE; ++cc) {
      const int s = tap * NCHTOT + cc;
      short8 a = *(const short8*)(a_base + (size_t)s * 512);
      short8 b0, b1;
      if (cc < NCHH) {
        b0 = *(const short8*)(bh0 + cc * 32);
        b1 = *(const short8*)(bh0 + 16 * kCHh + cc * 32);
      } else {
        b0 = *(const short8*)(bf0 + (cc - NCHH) * 32);
        b1 = *(const short8*)(bf0 + 16 * kCF + (cc - NCHH) * 32);
      }
      acc[0] = __builtin_amdgcn_mfma_f32_16x16x32_bf16(a, b0, acc[0], 0, 0, 0);
      acc[1] = __builtin_amdgcn_mfma_f32_16x16x32_bf16(a, b1, acc[1], 0, 0, 0);
    }
  }
}

// conv_zr: 4-way split-K; OC=256. grid (16, 96)
__global__ __launch_bounds__(256) void conv_zr_k(const unsigned short* __restrict__ hT,
                                                 const unsigned short* __restrict__ fcT,
                                                 const unsigned short* __restrict__ P,
                                                 const float* __restrict__ bzr,
                                                 float* __restrict__ zpre,
                                                 const float* __restrict__ hbuf,
                                                 unsigned short* __restrict__ rhT) {
  __shared__ f32x4 red[3][2][64];
  const int tid = threadIdx.x;
  const int wv = tid >> 6, lane = tid & 63;
  const int y = blockIdx.y >> 1, xbase = (blockIdx.y & 1) * 32;
  const int ot = blockIdx.x;
  f32x4 acc[2] = {{0.f,0.f,0.f,0.f},{0.f,0.f,0.f,0.f}};
  if (wv == 0)      conv_core32<0, 5, 4, 17>(hT, fcT, P, y, xbase, ot, lane, acc);
  else if (wv == 1) conv_core32<5, 9, 4, 17>(hT, fcT, P, y, xbase, ot, lane, acc);
  else if (wv == 2) conv_core32<9, 13, 4, 17>(hT, fcT, P, y, xbase, ot, lane, acc);
  else              conv_core32<13, 17, 4, 17>(hT, fcT, P, y, xbase, ot, lane, acc);
  if (wv != 0) {
    red[wv - 1][0][lane] = acc[0];
    red[wv - 1][1][lane] = acc[1];
  }
  __syncthreads();
  if (wv != 0) return;
#pragma unroll
  for (int j = 0; j < 3; ++j) {
    acc[0] += red[j][0][lane];
    acc[1] += red[j][1][lane];
  }
  const int m = lane & 15, kg = lane >> 4;
#pragma unroll
  for (int t = 0; t < 2; ++t)
#pragma unroll
    for (int r = 0; r < 4; ++r) {
      const int oc = ot * 16 + kg * 4 + r;
      const int pxx = xbase + t * 16 + m;
      const int px = y * kW + pxx;
      const float val = acc[t][r] + bzr[oc];
      if (oc < kHidden) {
        zpre[(size_t)oc * kHW + px] = val;
      } else {
        const float rg = 1.f / (1.f + expf(-val));
        const int ppix = (y + 1) * kWp2 + pxx + 1;
        rhT[(size_t)ppix * kCHh + oc - kHidden] =
            f2b(rg * hbuf[(size_t)(oc - kHidden) * kHW + px]);
      }
    }
}

// conv_q: 4-way split-K; OC=128. grid (8, 96)
__global__ __launch_bounds__(256) void conv_q_k(const unsigned short* __restrict__ rhT,
                                                const unsigned short* __restrict__ fcT,
                                                unsigned short* __restrict__ hT,
                                                const unsigned short* __restrict__ P,
                                                const float* __restrict__ bq,
                                                const float* __restrict__ zpre,
                                                float* __restrict__ hbuf) {
  __shared__ f32x4 red[3][2][64];
  const int tid = threadIdx.x;
  const int wv = tid >> 6, lane = tid & 63;
  const int y = blockIdx.y >> 1, xbase = (blockIdx.y & 1) * 32;
  const int ot = blockIdx.x;
  f32x4 acc[2] = {{0.f,0.f,0.f,0.f},{0.f,0.f,0.f,0.f}};
  if (wv == 0)      conv_core32<0, 5, 4, 17>(rhT, fcT, P, y, xbase, ot, lane, acc);
  else if (wv == 1) conv_core32<5, 9, 4, 17>(rhT, fcT, P, y, xbase, ot, lane, acc);
  else if (wv == 2) conv_core32<9, 13, 4, 17>(rhT, fcT, P, y, xbase, ot, lane, acc);
  else              conv_core32<13, 17, 4, 17>(rhT, fcT, P, y, xbase, ot, lane, acc);
  if (wv != 0) {
    red[wv - 1][0][lane] = acc[0];
    red[wv - 1][1][lane] = acc[1];
  }
  __syncthreads();
  if (wv != 0) return;
#pragma unroll
  for (int j = 0; j < 3; ++j) {
    acc[0] += red[j][0][lane];
    acc[1] += red[j][1][lane];
  }
  const int m = lane & 15, kg = lane >> 4;
#pragma unroll
  for (int t = 0; t < 2; ++t)
#pragma unroll
    for (int r = 0; r < 4; ++r) {
      const int oc = ot * 16 + kg * 4 + r;
      const int pxx = xbase + t * 16 + m;
      const int px = y * kW + pxx;
      const size_t off = (size_t)oc * kHW + px;
      const float q = acc[t][r] + bq[oc];
      const float zg = 1.f / (1.f + expf(-zpre[off]));
      const float hn = (1.f - zg) * hbuf[off] + zg * tanhf(q);
      hbuf[off] = hn;
      const int ppix = (y + 1) * kWp2 + pxx + 1;
      hT[(size_t)ppix * kCHh + oc] = f2b(hn);
    }
}

// conv_h + fused pose update (last-block completion). grid (4, 96) = 384 blocks
__global__ __launch_bounds__(256) void conv_h_k(const unsigned short* __restrict__ hT,
                                                const unsigned short* __restrict__ P,
                                                const float* __restrict__ bh,
                                                float* __restrict__ feat,
                                                float* __restrict__ conf,
                                                const float* __restrict__ Wfc,
                                                const float* __restrict__ bfc,
                                                float* __restrict__ pose,
                                                float* __restrict__ samp,
                                                float* __restrict__ out,
                                                unsigned int* __restrict__ cnt) {
  __shared__ f32x4 red[2][2][64];
  __shared__ unsigned int s_last;
  const int tid = threadIdx.x;
  const int wv = tid >> 6, lane = tid & 63;
  const int p = wv >> 1, half = wv & 1;
  const int y = blockIdx.y >> 1, xbase = (blockIdx.y & 1) * 32;
  const int ot = blockIdx.x * 2 + p;
  f32x4 acc[2] = {{0.f,0.f,0.f,0.f},{0.f,0.f,0.f,0.f}};
  if (half == 0) conv_core32<0, 2, 4, 4>(hT, hT, P, y, xbase, ot, lane, acc);
  else           conv_core32<2, 4, 4, 4>(hT, hT, P, y, xbase, ot, lane, acc);
  if (half == 1) {
    red[p][0][lane] = acc[0];
    red[p][1][lane] = acc[1];
  }
  __syncthreads();
  if (half == 0) {
    acc[0] += red[p][0][lane];
    acc[1] += red[p][1][lane];
    const int m = lane & 15, kg = lane >> 4;
#pragma unroll
    for (int r = 0; r < 4; ++r) {
      const int oc = ot * 16 + kg * 4 + r;
      const float bv = bh[oc];
      float v = fmaxf(acc[0][r] + bv, 0.f) + fmaxf(acc[1][r] + bv, 0.f);
      v += __shfl_xor(v, 1, 64);
      v += __shfl_xor(v, 2, 64);
      v += __shfl_xor(v, 4, 64);
      v += __shfl_xor(v, 8, 64);
      if (m == 0) atomicAdd(&feat[oc], v);
    }
  }
  // completion detection: last block performs the pose update
  __threadfence();
  __syncthreads();
  if (tid == 0) s_last = (atomicAdd(cnt, 1u) == 383u) ? 1u : 0u;
  __syncthreads();
  if (!s_last) return;

  __shared__ float s_d[7];
  __shared__ float s_pose[7];
  volatile const float* vfeat = feat;  // atomics bypass L1; force coherent reads
  if (tid < 7) {
    float s = 0.f;
    const float inv = 1.f / (float)kHW;
    for (int k = 0; k < kHidden; ++k) s += (vfeat[k] * inv) * Wfc[k * 7 + tid];
    s_d[tid] = 0.01f * (s + bfc[tid]);
  }
  __syncthreads();
  if (tid < kHidden) feat[tid] = 0.f;
  if (tid < 64) conf[tid] = 0.f;
  if (tid == 0) {
    float qc[4] = {pose[0], pose[1], pose[2], pose[3]};
    float tc[3] = {pose[4], pose[5], pose[6]};
    float dq[4] = {1.f + s_d[0], s_d[1], s_d[2], s_d[3]};
    float inv = 1.f / sqrtf(dq[0]*dq[0] + dq[1]*dq[1] + dq[2]*dq[2] + dq[3]*dq[3]);
    dq[0] *= inv; dq[1] *= inv; dq[2] *= inv; dq[3] *= inv;
    float dv[3] = {s_d[4], s_d[5], s_d[6]};
    float rv[3];
    d_qapply(qc, dv, rv);
    float tn[3] = {tc[0] + rv[0], tc[1] + rv[1], tc[2] + rv[2]};
    float qn[4];
    d_qmul(qc, dq, qn);
    float inv2 = 1.f / sqrtf(qn[0]*qn[0] + qn[1]*qn[1] + qn[2]*qn[2] + qn[3]*qn[3]);
    qn[0] *= inv2; qn[1] *= inv2; qn[2] *= inv2; qn[3] *= inv2;
    s_pose[0] = qn[0]; s_pose[1] = qn[1]; s_pose[2] = qn[2]; s_pose[3] = qn[3];
    s_pose[4] = tn[0]; s_pose[5] = tn[1]; s_pose[6] = tn[2];
    pose[0] = qn[0]; pose[1] = qn[1]; pose[2] = qn[2]; pose[3] = qn[3];
    pose[4] = tn[0]; pose[5] = tn[1]; pose[6] = tn[2];
    out[0] = qn[0]; out[1] = qn[1]; out[2] = qn[2]; out[3] = qn[3];
    out[4] = tn[0]; out[5] = tn[1]; out[6] = tn[2];
    *cnt = 0;  // reset for next iteration
  }
  __syncthreads();
  if (tid < kNS) sample_Rt(tid, s_pose, samp + tid * 12);
}

// ---------------- launch ----------------
extern "C" void kernel_launch(void* const* d_in, const int* in_sizes, int n_in,
                              void* d_out, int out_size, void* d_ws, size_t ws_size,
                              hipStream_t stream) {
  const float* frgb  = (const float*)d_in[0];
  const float* fdep  = (const float*)d_in[1];
  const float* depth = (const float*)d_in[2];
  const float* ctx   = (const float*)d_in[3];
  const float* intr  = (const float*)d_in[4];
  const float* Wz = (const float*)d_in[5];
  const float* bz = (const float*)d_in[6];
  const float* Wr = (const float*)d_in[7];
  const float* br = (const float*)d_in[8];
  const float* Wq = (const float*)d_in[9];
  const float* bq = (const float*)d_in[10];
  const float* Wh = (const float*)d_in[11];
  const float* bh = (const float*)d_in[12];
  const float* Wfc = (const float*)d_in[13];
  const float* bfc = (const float*)d_in[14];
  float* outp = (float*)d_out;

  float* ws = (float*)d_ws;
  unsigned short* us = (unsigned short*)d_ws;
  unsigned short* corr0 = us + U_CORR0;
  unsigned short* corr1 = us + U_CORR1;
  unsigned short* corr2 = us + U_CORR2;
  unsigned short* corr3 = us + U_CORR3;
  float* X    = ws + F_X;
  float* hbuf = ws + F_H;
  float* zpre = ws + F_ZPRE;
  unsigned short* fcT = us + U_FCT;
  unsigned short* hT  = us + U_HT;
  unsigned short* rhT = us + U_RHT;
  unsigned short* Pzr = us + U_PZR;
  unsigned short* Pq  = us + U_PQ;
  unsigned short* Ph  = us + U_PH;
  float* bzr  = ws + F_BZR;
  float* conf = ws + F_CONF;
  float* pose = ws + F_POSE;
  float* feat = ws + F_FEAT;
  float* samp = ws + F_SAMP;
  unsigned int* cnt = (unsigned int*)(ws + F_CNT);
  unsigned short* fdT  = us + U_FDT;
  unsigned short* qT   = us + U_QT;
  unsigned short* Sbox = us + U_SBOX;  // overlays fdT/qT after setup

  init_k<<<1536, 256, 0, stream>>>(ctx, bz, br, depth, intr, hbuf,
                                   (unsigned int*)fcT, fcT, bzr, X, conf, feat,
                                   pose, samp, cnt);
  setup2_k<<<(450048 + 255) / 256, 256, 0, stream>>>(ctx, fcT, Wz, Wr, Wq, Wh,
                                                     Pzr, Pq, Ph);
  t_bf16_k<<<dim3(48, 8), 256, 0, stream>>>(fdep, frgb, fdT, qT);
  corr_mfma_k<<<dim3(24, 24), 256, 0, stream>>>(fdT, qT, corr0);
  boxbuild_k<<<kHW, 256, 0, stream>>>(corr0, corr1, corr2, corr3, Sbox);

  for (int it = 0; it < kIters; ++it) {
    conf_k<<<444, 256, 0, stream>>>(Sbox, X, samp, intr, conf);
    fused_k<<<kHW, 256, 0, stream>>>(corr0, corr1, corr2, corr3, X, samp, intr,
                                     conf, fcT);
    conv_zr_k<<<dim3(16, 96), 256, 0, stream>>>(hT, fcT, Pzr, bzr, zpre, hbuf, rhT);
    conv_q_k<<<dim3(8, 96), 256, 0, stream>>>(rhT, fcT, hT, Pq, bq, zpre, hbuf);
    conv_h_k<<<dim3(4, 96), 256, 0, stream>>>(hT, Ph, bh, feat, conf, Wfc, bfc,
                                              pose, samp, outp, cnt);
  }
}

// Round 14
// 775.634 us; speedup vs baseline: 1.1075x; 1.1075x over previous
//
#include <hip/hip_runtime.h>
#include <math.h>

// ---------------- problem constants ----------------
constexpr int kH = 48, kW = 64, kHW = 3072, kC = 256;
constexpr int kHidden = 128, kCtx = 64;
constexpr int kP = 81, kCorrDim = 324;  // 81*4
constexpr int kNS = 37, kIters = 4;
constexpr int kGin = kHidden + kCorrDim + kCtx;  // 516
// padded spatial domain for conv inputs
constexpr int kWp2 = 66, kHp2 = 50, kPix = 3300;  // (48+2)x(64+2)
constexpr int kCF = 416;   // fused(324)+ctx(64)+pad(28) = 13*32
constexpr int kCHh = 128;  // h / rh channels = 4*32

// box-filtered pyramid (padded +10 each dim), per source pixel:
// L0 74x58, L1 42x34, L2 26x22, L3 18x16 -> 6580 entries
constexpr int kSB0 = 0, kSB1 = 4292, kSB2 = 5720, kSB3 = 6292, kSBTot = 6580;
// horizontal-pass buffer (padded cols, unpadded rows): 74x48, 42x24, 26x12, 18x6
constexpr int kHB0 = 0, kHB1 = 3552, kHB2 = 4560, kHB3 = 4872, kHBTot = 4980;

// ---------------- workspace layout ----------------
constexpr size_t U_CORR0 = 0;
constexpr size_t U_CORR1 = U_CORR0 + (size_t)kHW * 3072;
constexpr size_t U_CORR2 = U_CORR1 + (size_t)kHW * 768;
constexpr size_t U_CORR3 = U_CORR2 + (size_t)kHW * 192;
constexpr size_t U_END0  = U_CORR3 + (size_t)kHW * 48;
constexpr size_t F_X     = U_END0 / 2;
constexpr size_t F_H     = F_X + (size_t)kHW * 3;
constexpr size_t F_ZPRE  = F_H + (size_t)kHidden * kHW;
constexpr size_t F_END1  = F_ZPRE + (size_t)kHidden * kHW;
constexpr size_t U_FCT   = F_END1 * 2;                    // 3300*416
constexpr size_t U_HT    = U_FCT + (size_t)kPix * kCF;    // 3300*128
constexpr size_t U_RHT   = U_HT + (size_t)kPix * kCHh;    // 3300*128
constexpr size_t U_PZR   = U_RHT + (size_t)kPix * kCHh;
constexpr size_t U_PQ    = U_PZR + (size_t)16 * 9 * 17 * 512;
constexpr size_t U_PH    = U_PQ + (size_t)8 * 9 * 17 * 512;
constexpr size_t U_END2  = U_PH + (size_t)8 * 9 * 4 * 512;
constexpr size_t F_BZR   = U_END2 / 2 + 1;
constexpr size_t F_CONF  = F_BZR + 256;
constexpr size_t F_POSE  = F_CONF + 64;
constexpr size_t F_FEAT  = F_POSE + 16;
constexpr size_t F_SAMP  = F_FEAT + 128;   // 37*12
constexpr size_t F_END3  = F_SAMP + 448;
constexpr size_t U_FDT   = F_END3 * 2;
constexpr size_t U_QT    = U_FDT + (size_t)kHW * kC;
constexpr size_t U_SBOX  = U_FDT;  // overlays fdT/qT after setup

typedef __attribute__((ext_vector_type(8))) short short8;
typedef __attribute__((ext_vector_type(4))) float f32x4;

__device__ inline unsigned short f2b(float f) {
  unsigned int u = __float_as_uint(f);
  unsigned int r = u + 0x7FFF + ((u >> 16) & 1);
  return (unsigned short)(r >> 16);
}
__device__ inline float b2f(unsigned short u) {
  return __uint_as_float(((unsigned int)u) << 16);
}
__device__ inline int clampi(int v, int lo, int hi) { return min(max(v, lo), hi); }

// ---------------- sample templates ----------------
__constant__ float c_rot[12][3] = {
  {0,0,0},{0,0,0},{0,0,0},{0,0,0},{0,0,0},{0,0,0},
  {1,0,0},{-1,0,0},{0,1,0},{0,-1,0},{0,0,1},{0,0,-1}};
__constant__ float c_trs[12][3] = {
  {1,0,0},{-1,0,0},{0,1,0},{0,-1,0},{0,0,1},{0,0,-1},
  {0,0,0},{0,0,0},{0,0,0},{0,0,0},{0,0,0},{0,0,0}};

// ---------------- device helpers ----------------
__device__ inline void d_qmul(const float* q, const float* r, float* o) {
  o[0] = q[0]*r[0] - q[1]*r[1] - q[2]*r[2] - q[3]*r[3];
  o[1] = q[0]*r[1] + q[1]*r[0] + q[2]*r[3] - q[3]*r[2];
  o[2] = q[0]*r[2] - q[1]*r[3] + q[2]*r[0] + q[3]*r[1];
  o[3] = q[0]*r[3] + q[1]*r[2] - q[2]*r[1] + q[3]*r[0];
}
__device__ inline void d_qapply(const float* q, const float* v, float* o) {
  float a0 = -q[1]*v[0] - q[2]*v[1] - q[3]*v[2];
  float a1 =  q[0]*v[0] + q[2]*v[2] - q[3]*v[1];
  float a2 =  q[0]*v[1] - q[1]*v[2] + q[3]*v[0];
  float a3 =  q[0]*v[2] + q[1]*v[1] - q[2]*v[0];
  o[0] = -a0*q[1] + a1*q[0] - a2*q[3] + a3*q[2];
  o[1] = -a0*q[2] + a1*q[3] + a2*q[0] - a3*q[1];
  o[2] = -a0*q[3] - a1*q[2] + a2*q[1] + a3*q[0];
}
__device__ inline void d_intr(const float* intr, float& fx, float& fy, float& cx, float& cy) {
  fx = 60.f + 40.f*intr[0];
  fy = 60.f + 40.f*intr[1];
  cx = 32.f + 4.f*(intr[2] - 0.5f);
  cy = 24.f + 4.f*(intr[3] - 0.5f);
}
__device__ inline void sample_Rt(int t, const float* __restrict__ pose, float* S) {
  float qc[4] = {pose[0], pose[1], pose[2], pose[3]};
  float tc[3] = {pose[4], pose[5], pose[6]};
  float dq[4], dt[3];
  if (t == 36) {
    dq[0] = 1.f; dq[1] = dq[2] = dq[3] = 0.f;
    dt[0] = dt[1] = dt[2] = 0.f;
  } else {
    int j = t / 3, k = t % 3;
    float sc = (k == 0) ? 0.25f : ((k == 1) ? 1.f : 4.f);
    float rx = c_rot[j][0], ry = c_rot[j][1], rz = c_rot[j][2];
    float nrm = sqrtf(rx*rx + ry*ry + rz*rz);
    float axn = fmaxf(nrm, 1e-8f);
    float ax = rx / axn, ay = ry / axn, az = rz / axn;
    float ha = 0.02f * sc * 0.5f;
    float sh = sinf(ha), ch = cosf(ha);
    dq[0] = ch; dq[1] = ax * sh; dq[2] = ay * sh; dq[3] = az * sh;
    dt[0] = c_trs[j][0] * (0.02f * sc);
    dt[1] = c_trs[j][1] * (0.02f * sc);
    dt[2] = c_trs[j][2] * (0.02f * sc);
  }
  float qn[4];
  d_qmul(qc, dq, qn);
  float inv = 1.f / sqrtf(qn[0]*qn[0] + qn[1]*qn[1] + qn[2]*qn[2] + qn[3]*qn[3]);
  qn[0] *= inv; qn[1] *= inv; qn[2] *= inv; qn[3] *= inv;
  float tr[3];
  d_qapply(qc, dt, tr);
  float w = qn[0], x = qn[1], y = qn[2], z = qn[3];
  S[0] = 1.f - 2.f*(y*y + z*z); S[1] = 2.f*(x*y - w*z);       S[2] = 2.f*(x*z + w*y);
  S[3] = 2.f*(x*y + w*z);       S[4] = 1.f - 2.f*(x*x + z*z); S[5] = 2.f*(y*z - w*x);
  S[6] = 2.f*(x*z - w*y);       S[7] = 2.f*(y*z + w*x);       S[8] = 1.f - 2.f*(x*x + y*y);
  S[9]  = tc[0] + tr[0];
  S[10] = tc[1] + tr[1];
  S[11] = tc[2] + tr[2];
}
__device__ inline void project_uv(const float* S, const float* Xp, const float* intr,
                                  float& u, float& v) {
  float xc0 = S[0]*Xp[0] + S[1]*Xp[1] + S[2]*Xp[2] + S[9];
  float xc1 = S[3]*Xp[0] + S[4]*Xp[1] + S[5]*Xp[2] + S[10];
  float xc2 = S[6]*Xp[0] + S[7]*Xp[1] + S[8]*Xp[2] + S[11];
  float z = fmaxf(xc2, 0.1f);
  float fx, fy, cx, cy;
  d_intr(intr, fx, fy, cx, cy);
  u = fx * xc0 / z + cx;
  v = fy * xc1 / z + cy;
}

// ---------------- init (merged); also precomputes samp for identity pose ----------------
__global__ void init_k(const float* __restrict__ ctx, const float* __restrict__ bz,
                       const float* __restrict__ br, const float* __restrict__ depth,
                       const float* __restrict__ intr, float* __restrict__ h,
                       unsigned int* __restrict__ zbase, unsigned short* __restrict__ fcT,
                       float* __restrict__ bzr, float* __restrict__ X,
                       float* __restrict__ conf, float* __restrict__ feat,
                       float* __restrict__ pose, float* __restrict__ samp) {
  const size_t nz = ((size_t)kPix * (kCF + 2 * kCHh)) / 2;  // uint count
  for (size_t i = blockIdx.x * blockDim.x + threadIdx.x; i < nz;
       i += (size_t)gridDim.x * blockDim.x)
    zbase[i] = 0;
  int idx = blockIdx.x * blockDim.x + threadIdx.x;
  if (idx < kHidden * kHW) h[idx] = 0.f;
  if (idx < kHW) {
    float fx, fy, cx, cy;
    d_intr(intr, fx, fy, cx, cy);
    float d = 4.f + 20.f * depth[idx];
    float u = (float)(idx % kW), v = (float)(idx / kW);
    X[idx*3+0] = (u - cx) / fx * d;
    X[idx*3+1] = (v - cy) / fy * d;
    X[idx*3+2] = d;
  }
  if (idx < 256) bzr[idx] = (idx < 128) ? bz[idx] : br[idx - 128];
  if (idx < 64) conf[idx] = 0.f;
  if (idx < 128) feat[idx] = 0.f;
  if (idx < kNS) {
    const float ipose[7] = {1.f, 0.f, 0.f, 0.f, 0.f, 0.f, 0.f};
    sample_Rt(idx, ipose, samp + idx * 12);
  }
  if (idx == 0) {
    pose[0] = 1.f;
    for (int j = 1; j < 7; ++j) pose[j] = 0.f;
  }
}
// ctx copy AFTER zeroing (separate dispatch avoids race)
__global__ void initctx_k(const float* __restrict__ ctx, unsigned short* __restrict__ fcT) {
  int idx = blockIdx.x * blockDim.x + threadIdx.x;
  if (idx < kHW * 64) {
    int p = idx >> 6, c = idx & 63;
    int ppix = ((p >> 6) + 1) * kWp2 + (p & 63) + 1;
    fcT[(size_t)ppix * kCF + kCorrDim + c] = f2b(ctx[(size_t)c * kHW + p]);
  }
}

// ---------------- weight prepack (tile16-major): P[ot][tap][cc][m][g][8] ----------------
__global__ void pack_k(const float* __restrict__ W0, const float* __restrict__ W1,
                       int ocSplit, int OC, int NCH, int Cin,
                       unsigned short* __restrict__ P) {
  int idx = blockIdx.x * blockDim.x + threadIdx.x;
  int total = (OC / 16) * 9 * NCH * 64;
  if (idx >= total) return;
  int g = idx & 3;
  int m = (idx >> 2) & 15;
  int rest = idx >> 6;
  int cc = rest % NCH;
  int rest2 = rest / NCH;
  int tap = rest2 % 9;
  int ot = rest2 / 9;
  int oc = ot * 16 + m;
  union { unsigned short u[8]; uint4 q; } v;
#pragma unroll
  for (int j = 0; j < 8; ++j) {
    int ci = cc * 32 + g * 8 + j;
    float w = 0.f;
    if (ci < Cin)
      w = (oc < ocSplit) ? W0[((size_t)oc * Cin + ci) * 9 + tap]
                         : W1[((size_t)(oc - ocSplit) * Cin + ci) * 9 + tap];
    v.u[j] = f2b(w);
  }
  *(uint4*)&P[(size_t)idx * 8] = v.q;
}

// ---------------- fp32 [C][HW] -> bf16 [HW][C] transpose ----------------
__global__ __launch_bounds__(256) void t_bf16_k(const float* __restrict__ src,
                                                unsigned short* __restrict__ dst) {
  __shared__ float t[64][65];
  const int tid = threadIdx.x;
  const int p0 = blockIdx.x * 64, c0 = blockIdx.y * 64;
  const int tx = tid & 63, ty = tid >> 6;
  for (int cl = ty; cl < 64; cl += 4)
    t[cl][tx] = src[(size_t)(c0 + cl) * kHW + p0 + tx];
  __syncthreads();
  for (int pl = ty; pl < 64; pl += 4)
    dst[(size_t)(p0 + pl) * kC + c0 + tx] = f2b(t[tx][pl]);
}

// ---------------- corr GEMM via MFMA -> bf16 pyramid L0 ----------------
__global__ __launch_bounds__(256) void corr_mfma_k(const unsigned short* __restrict__ fdT,
                                                   const unsigned short* __restrict__ qT,
                                                   unsigned short* __restrict__ Cg) {
  const int tid = threadIdx.x;
  const int wv = tid >> 6, lane = tid & 63;
  const int m = lane & 15, kg = lane >> 4;
  const int i0 = blockIdx.y * 128 + wv * 32;
  const int q0 = blockIdx.x * 128;

  f32x4 acc[2][8];
#pragma unroll
  for (int t = 0; t < 2; ++t)
#pragma unroll
    for (int u = 0; u < 8; ++u) acc[t][u] = (f32x4){0.f, 0.f, 0.f, 0.f};

#pragma unroll
  for (int kc = 0; kc < 8; ++kc) {
    const int kb = kc * 32 + kg * 8;
    short8 a[2], b[8];
#pragma unroll
    for (int t = 0; t < 2; ++t)
      a[t] = *(const short8*)&fdT[(size_t)(i0 + t * 16 + m) * kC + kb];
#pragma unroll
    for (int u = 0; u < 8; ++u)
      b[u] = *(const short8*)&qT[(size_t)(q0 + u * 16 + m) * kC + kb];
#pragma unroll
    for (int t = 0; t < 2; ++t)
#pragma unroll
      for (int u = 0; u < 8; ++u)
        acc[t][u] = __builtin_amdgcn_mfma_f32_16x16x32_bf16(a[t], b[u], acc[t][u], 0, 0, 0);
  }
  const float S = 0.0625f;
#pragma unroll
  for (int t = 0; t < 2; ++t)
#pragma unroll
    for (int u = 0; u < 8; ++u)
#pragma unroll
      for (int r = 0; r < 4; ++r)
        Cg[(size_t)(i0 + t * 16 + kg * 4 + r) * kHW + q0 + u * 16 + m] = f2b(acc[t][u][r] * S);
}

// ---------------- box-filter build + pyramid pooling, one block per source pixel ----------------
template<int HL>
__device__ inline void colpref(float* base, int Wp) {
  float v[HL];
#pragma unroll
  for (int y = 0; y < HL; ++y) v[y] = base[(size_t)y * Wp];
  float run = 0.f;
#pragma unroll
  for (int y = 0; y < HL; ++y) {
    run += v[y];
    base[(size_t)y * Wp] = run;
  }
}

__global__ __launch_bounds__(256) void boxbuild_k(const unsigned short* __restrict__ corr0,
                                                  unsigned short* __restrict__ corr1,
                                                  unsigned short* __restrict__ corr2,
                                                  unsigned short* __restrict__ corr3,
                                                  unsigned short* __restrict__ Sbox) {
  __shared__ float pyr[4080];
  __shared__ float hb[kHBTot];
  const int i = blockIdx.x;
  const int tid = threadIdx.x;
  const int wv = tid >> 6, lane = tid & 63;

  for (int idx = tid; idx < 3072; idx += 256)
    pyr[idx] = b2f(corr0[(size_t)i * 3072 + idx]);
  __syncthreads();

  for (int c = tid; c < 768; c += 256) {
    int y = c >> 5, x = c & 31;
    float v = 0.25f * (pyr[(2*y)*64 + 2*x] + pyr[(2*y)*64 + 2*x + 1] +
                       pyr[(2*y+1)*64 + 2*x] + pyr[(2*y+1)*64 + 2*x + 1]);
    unsigned short b = f2b(v);
    corr1[(size_t)i * 768 + c] = b;
    pyr[3072 + c] = b2f(b);
  }
  __syncthreads();
  for (int c = tid; c < 192; c += 256) {
    int y = c >> 4, x = c & 15;
    const float* p = pyr + 3072;
    float v = 0.25f * (p[(2*y)*32 + 2*x] + p[(2*y)*32 + 2*x + 1] +
                       p[(2*y+1)*32 + 2*x] + p[(2*y+1)*32 + 2*x + 1]);
    unsigned short b = f2b(v);
    corr2[(size_t)i * 192 + c] = b;
    pyr[3840 + c] = b2f(b);
  }
  __syncthreads();
  for (int c = tid; c < 48; c += 256) {
    int y = c >> 3, x = c & 7;
    const float* p = pyr + 3840;
    float v = 0.25f * (p[(2*y)*16 + 2*x] + p[(2*y)*16 + 2*x + 1] +
                       p[(2*y+1)*16 + 2*x] + p[(2*y+1)*16 + 2*x + 1]);
    unsigned short b = f2b(v);
    corr3[(size_t)i * 48 + c] = b;
    pyr[4032 + c] = b2f(b);
  }
  __syncthreads();

  const int lvl_off[4] = {0, 3072, 3840, 4032};
  for (int r = wv; r < 90; r += 4) {
    int lvl, y;
    if (r < 48)      { lvl = 0; y = r; }
    else if (r < 72) { lvl = 1; y = r - 48; }
    else if (r < 84) { lvl = 2; y = r - 72; }
    else             { lvl = 3; y = r - 84; }
    const int Wl = kW >> lvl;
    float* row = &pyr[lvl_off[lvl] + y * Wl];
    float v = (lane < Wl) ? row[lane] : 0.f;
#pragma unroll
    for (int o = 1; o < 64; o <<= 1) {
      float tv = __shfl_up(v, o, 64);
      if (lane >= o) v += tv;
    }
    if (lane < Wl) row[lane] = v;
  }
  __syncthreads();

  for (int c = tid; c < 3552; c += 256) {
    int y = c / 74, as = c % 74;
    const float* pref = &pyr[y * 64];
    float Hv = 0.f;
    if (as >= 1) Hv = pref[min(63, as - 1)];
    if (as >= 10) Hv -= pref[as - 10];
    hb[kHB0 + c] = Hv;
  }
  for (int c = tid; c < 1008; c += 256) {
    int y = c / 42, as = c % 42;
    const float* pref = &pyr[3072 + y * 32];
    float Hv = 0.f;
    if (as >= 1) Hv = pref[min(31, as - 1)];
    if (as >= 10) Hv -= pref[as - 10];
    hb[kHB1 + c] = Hv;
  }
  for (int c = tid; c < 312; c += 256) {
    int y = c / 26, as = c % 26;
    const float* pref = &pyr[3840 + y * 16];
    float Hv = 0.f;
    if (as >= 1) Hv = pref[min(15, as - 1)];
    if (as >= 10) Hv -= pref[as - 10];
    hb[kHB2 + c] = Hv;
  }
  for (int c = tid; c < 108; c += 256) {
    int y = c / 18, as = c % 18;
    const float* pref = &pyr[4032 + y * 8];
    float Hv = 0.f;
    if (as >= 1) Hv = pref[min(7, as - 1)];
    if (as >= 10) Hv -= pref[as - 10];
    hb[kHB3 + c] = Hv;
  }
  __syncthreads();

  if (tid < 160) {
    if (tid < 74)       colpref<48>(hb + kHB0 + tid, 74);
    else if (tid < 116) colpref<24>(hb + kHB1 + (tid - 74), 42);
    else if (tid < 142) colpref<12>(hb + kHB2 + (tid - 116), 26);
    else                colpref<6>(hb + kHB3 + (tid - 142), 18);
  }
  __syncthreads();

  unsigned short* out = Sbox + (size_t)i * kSBTot;
  for (int c = tid; c < 4292; c += 256) {
    int bp = c / 74, as = c % 74;
    const float* col = &hb[kHB0 + as];
    float S = 0.f;
    if (bp >= 1) S = col[min(47, bp - 1) * 74];
    if (bp >= 10) S -= col[(bp - 10) * 74];
    out[kSB0 + c] = f2b(S);
  }
  for (int c = tid; c < 1428; c += 256) {
    int bp = c / 42, as = c % 42;
    const float* col = &hb[kHB1 + as];
    float S = 0.f;
    if (bp >= 1) S = col[min(23, bp - 1) * 42];
    if (bp >= 10) S -= col[(bp - 10) * 42];
    out[kSB1 + c] = f2b(S);
  }
  for (int c = tid; c < 572; c += 256) {
    int bp = c / 26, as = c % 26;
    const float* col = &hb[kHB2 + as];
    float S = 0.f;
    if (bp >= 1) S = col[min(11, bp - 1) * 26];
    if (bp >= 10) S -= col[(bp - 10) * 26];
    out[kSB2 + c] = f2b(S);
  }
  for (int c = tid; c < 288; c += 256) {
    int bp = c / 18, as = c % 18;
    const float* col = &hb[kHB3 + as];
    float S = 0.f;
    if (bp >= 1) S = col[min(5, bp - 1) * 18];
    if (bp >= 10) S -= col[(bp - 10) * 18];
    out[kSB3 + c] = f2b(S);
  }
}

// ---------------- conf: one thread per (sample, pixel); 16 Sbox reads ----------------
__global__ __launch_bounds__(256) void conf_k(const unsigned short* __restrict__ Sbox,
                                              const float* __restrict__ X,
                                              const float* __restrict__ samp,
                                              const float* __restrict__ intr,
                                              float* __restrict__ conf) {
  const int idx = blockIdx.x * 256 + threadIdx.x;
  const int n = idx / kHW, i = idx - n * kHW;
  const float* S = samp + n * 12;
  float Xp[3] = {X[i*3], X[i*3+1], X[i*3+2]};
  float u, v;
  project_uv(S, Xp, intr, u, v);
  const unsigned short* sb = Sbox + (size_t)i * kSBTot;
  float tot = 0.f;
#pragma unroll
  for (int l = 0; l < 4; ++l) {
    const int Wp = (kW >> l) + 10, Hp = (kH >> l) + 10;
    const int so = (l == 0) ? kSB0 : (l == 1) ? kSB1 : (l == 2) ? kSB2 : kSB3;
    const float s = (float)(1 << l);
    const float bx = u / s, by = v / s;
    const float fbx = floorf(bx), fby = floorf(by);
    const int x0 = (int)fbx, y0 = (int)fby;
    const float fx = bx - fbx, fy = by - fby;
    const int xa = clampi(x0 + 5, 0, Wp - 1), xb = clampi(x0 + 6, 0, Wp - 1);
    const int ya = clampi(y0 + 5, 0, Hp - 1), yb = clampi(y0 + 6, 0, Hp - 1);
    const float s00 = b2f(sb[so + ya * Wp + xa]), s10 = b2f(sb[so + ya * Wp + xb]);
    const float s01 = b2f(sb[so + yb * Wp + xa]), s11 = b2f(sb[so + yb * Wp + xb]);
    tot += (1.f - fx) * (1.f - fy) * s00 + fx * (1.f - fy) * s10 +
           (1.f - fx) * fy * s01 + fx * fy * s11;
  }
#pragma unroll
  for (int o = 32; o; o >>= 1) tot += __shfl_xor(tot, o, 64);
  if ((threadIdx.x & 63) == 0) atomicAdd(&conf[n], tot);
}

// ---------------- fused corr features (inline top-k) -> fcT interior ----------------
__global__ __launch_bounds__(256) void fused_k(const unsigned short* __restrict__ corr0,
                                               const unsigned short* __restrict__ corr1,
                                               const unsigned short* __restrict__ corr2,
                                               const unsigned short* __restrict__ corr3,
                                               const float* __restrict__ X,
                                               const float* __restrict__ samp,
                                               const float* __restrict__ intr,
                                               const float* __restrict__ conf,
                                               unsigned short* __restrict__ fcT) {
  __shared__ float win[12][10][12];
  __shared__ float s_fx[12], s_fy[12];
  __shared__ int   s_ix[12], s_iy[12];
  __shared__ float s_w[3];
  __shared__ int   s_id[3];
  const int i = blockIdx.x;
  const int tid = threadIdx.x;

  if (tid == 0) {
    const float scale = 1.f / ((float)kHW * (float)kCorrDim);
    float c[kNS];
    for (int n = 0; n < kNS; ++n) c[n] = conf[n] * scale;
    int id[3] = {-1, -1, -1};
    float v[3];
    for (int k = 0; k < 3; ++k) {
      float best = -1e30f;
      int bi = -1;
      for (int n = 0; n < kNS; ++n) {
        if (n == id[0] || n == id[1] || n == id[2]) continue;
        if (c[n] > best) { best = c[n]; bi = n; }
      }
      v[k] = best;
      id[k] = bi;
    }
    float m = v[0];
    float e0 = expf(v[0] - m), e1 = expf(v[1] - m), e2 = expf(v[2] - m);
    float s = e0 + e1 + e2;
    s_w[0] = e0 / s; s_w[1] = e1 / s; s_w[2] = e2 / s;
    s_id[0] = id[0]; s_id[1] = id[1]; s_id[2] = id[2];
  }
  __syncthreads();

  if (tid < 3) {
    const float* S = samp + s_id[tid] * 12;
    float Xp[3] = {X[i*3], X[i*3+1], X[i*3+2]};
    float u, v;
    project_uv(S, Xp, intr, u, v);
#pragma unroll
    for (int l = 0; l < 4; ++l) {
      float s = (float)(1 << l);
      float bx = u / s, by = v / s;
      float fbx = floorf(bx), fby = floorf(by);
      s_ix[tid*4 + l] = (int)fbx;
      s_iy[tid*4 + l] = (int)fby;
      s_fx[tid*4 + l] = bx - fbx;
      s_fy[tid*4 + l] = by - fby;
    }
  }
  __syncthreads();

  for (int sidx = tid; sidx < 1200; sidx += 256) {
    const int w = sidx / 100, rem = sidx % 100;
    const int rr = rem / 10, cc = rem % 10;
    const int lvl = w & 3;
    const int Wl = kW >> lvl, Hl = kH >> lvl;
    const unsigned short* base =
        (lvl == 0) ? corr0 : (lvl == 1) ? corr1 : (lvl == 2) ? corr2 : corr3;
    const int y = s_iy[w] - 4 + rr;
    const int x = s_ix[w] - 4 + cc;
    float v = 0.f;
    if (y >= 0 && y < Hl && x >= 0 && x < Wl)
      v = b2f(base[(size_t)i * (Hl * Wl) + y * Wl + x]);
    win[w][rr][cc] = v;
  }
  __syncthreads();

  const int ppix = ((i >> 6) + 1) * kWp2 + (i & 63) + 1;
  for (int d = tid; d < kCorrDim; d += 256) {
    const int lvl = d / kP;
    const int o = d % kP;
    const int oyi = o / 9, oxi = o % 9;
    float val = 0.f;
#pragma unroll
    for (int k = 0; k < 3; ++k) {
      const int w = k * 4 + lvl;
      const float fx = s_fx[w], fy = s_fy[w];
      const float w00 = (1.f - fx) * (1.f - fy), w10 = fx * (1.f - fy);
      const float w01 = (1.f - fx) * fy, w11 = fx * fy;
      val += s_w[k] * (w00 * win[w][oyi][oxi] + w10 * win[w][oyi][oxi + 1] +
                       w01 * win[w][oyi + 1][oxi] + w11 * win[w][oyi + 1][oxi + 1]);
    }
    fcT[(size_t)ppix * kCF + d] = f2b(val);
  }
}

// ---------------- LDS-free maskless conv core: wave = 16 oc x 32 px, cc range ----------------
template<int CCB, int CCE, int NCHH, int NCHTOT>
__device__ inline void conv_core32(const unsigned short* __restrict__ srcH,
                                   const unsigned short* __restrict__ srcF,
                                   const unsigned short* __restrict__ A,
                                   int y, int xbase, int ot, int lane,
                                   f32x4 (&acc)[2]) {
  const int m = lane & 15, kg = lane >> 4;
  const unsigned short* a_base = A + (size_t)ot * (9 * NCHTOT * 512) + m * 32 + kg * 8;
  const int pix0 = (y + 1) * kWp2 + (xbase + 1) + m;
#pragma unroll
  for (int tap = 0; tap < 9; ++tap) {
    const int dy = tap / 3 - 1, dx = tap % 3 - 1;
    const int po = pix0 + dy * kWp2 + dx;
    const unsigned short* bh0 = srcH + (size_t)po * kCHh + kg * 8;
    const unsigned short* bf0 = srcF + (size_t)po * kCF + kg * 8;
#pragma unroll
    for (int cc = CCB; cc < CCE; ++cc) {
      const int s = tap * NCHTOT + cc;
      short8 a = *(const short8*)(a_base + (size_t)s * 512);
      short8 b0, b1;
      if (cc < NCHH) {
        b0 = *(const short8*)(bh0 + cc * 32);
        b1 = *(const short8*)(bh0 + 16 * kCHh + cc * 32);
      } else {
        b0 = *(const short8*)(bf0 + (cc - NCHH) * 32);
        b1 = *(const short8*)(bf0 + 16 * kCF + (cc - NCHH) * 32);
      }
      acc[0] = __builtin_amdgcn_mfma_f32_16x16x32_bf16(a, b0, acc[0], 0, 0, 0);
      acc[1] = __builtin_amdgcn_mfma_f32_16x16x32_bf16(a, b1, acc[1], 0, 0, 0);
    }
  }
}

// conv_zr: 4-way split-K; OC=256. grid (16, 96)
__global__ __launch_bounds__(256) void conv_zr_k(const unsigned short* __restrict__ hT,
                                                 const unsigned short* __restrict__ fcT,
                                                 const unsigned short* __restrict__ P,
                                                 const float* __restrict__ bzr,
                                                 float* __restrict__ zpre,
                                                 const float* __restrict__ hbuf,
                                                 unsigned short* __restrict__ rhT) {
  __shared__ f32x4 red[3][2][64];
  const int tid = threadIdx.x;
  const int wv = tid >> 6, lane = tid & 63;
  const int y = blockIdx.y >> 1, xbase = (blockIdx.y & 1) * 32;
  const int ot = blockIdx.x;
  f32x4 acc[2] = {{0.f,0.f,0.f,0.f},{0.f,0.f,0.f,0.f}};
  if (wv == 0)      conv_core32<0, 5, 4, 17>(hT, fcT, P, y, xbase, ot, lane, acc);
  else if (wv == 1) conv_core32<5, 9, 4, 17>(hT, fcT, P, y, xbase, ot, lane, acc);
  else if (wv == 2) conv_core32<9, 13, 4, 17>(hT, fcT, P, y, xbase, ot, lane, acc);
  else              conv_core32<13, 17, 4, 17>(hT, fcT, P, y, xbase, ot, lane, acc);
  if (wv != 0) {
    red[wv - 1][0][lane] = acc[0];
    red[wv - 1][1][lane] = acc[1];
  }
  __syncthreads();
  if (wv != 0) return;
#pragma unroll
  for (int j = 0; j < 3; ++j) {
    acc[0] += red[j][0][lane];
    acc[1] += red[j][1][lane];
  }
  const int m = lane & 15, kg = lane >> 4;
#pragma unroll
  for (int t = 0; t < 2; ++t)
#pragma unroll
    for (int r = 0; r < 4; ++r) {
      const int oc = ot * 16 + kg * 4 + r;
      const int pxx = xbase + t * 16 + m;
      const int px = y * kW + pxx;
      const float val = acc[t][r] + bzr[oc];
      if (oc < kHidden) {
        zpre[(size_t)oc * kHW + px] = val;
      } else {
        const float rg = 1.f / (1.f + expf(-val));
        const int ppix = (y + 1) * kWp2 + pxx + 1;
        rhT[(size_t)ppix * kCHh + oc - kHidden] =
            f2b(rg * hbuf[(size_t)(oc - kHidden) * kHW + px]);
      }
    }
}

// conv_q: 4-way split-K; OC=128. grid (8, 96)
__global__ __launch_bounds__(256) void conv_q_k(const unsigned short* __restrict__ rhT,
                                                const unsigned short* __restrict__ fcT,
                                                unsigned short* __restrict__ hT,
                                                const unsigned short* __restrict__ P,
                                                const float* __restrict__ bq,
                                                const float* __restrict__ zpre,
                                                float* __restrict__ hbuf) {
  __shared__ f32x4 red[3][2][64];
  const int tid = threadIdx.x;
  const int wv = tid >> 6, lane = tid & 63;
  const int y = blockIdx.y >> 1, xbase = (blockIdx.y & 1) * 32;
  const int ot = blockIdx.x;
  f32x4 acc[2] = {{0.f,0.f,0.f,0.f},{0.f,0.f,0.f,0.f}};
  if (wv == 0)      conv_core32<0, 5, 4, 17>(rhT, fcT, P, y, xbase, ot, lane, acc);
  else if (wv == 1) conv_core32<5, 9, 4, 17>(rhT, fcT, P, y, xbase, ot, lane, acc);
  else if (wv == 2) conv_core32<9, 13, 4, 17>(rhT, fcT, P, y, xbase, ot, lane, acc);
  else              conv_core32<13, 17, 4, 17>(rhT, fcT, P, y, xbase, ot, lane, acc);
  if (wv != 0) {
    red[wv - 1][0][lane] = acc[0];
    red[wv - 1][1][lane] = acc[1];
  }
  __syncthreads();
  if (wv != 0) return;
#pragma unroll
  for (int j = 0; j < 3; ++j) {
    acc[0] += red[j][0][lane];
    acc[1] += red[j][1][lane];
  }
  const int m = lane & 15, kg = lane >> 4;
#pragma unroll
  for (int t = 0; t < 2; ++t)
#pragma unroll
    for (int r = 0; r < 4; ++r) {
      const int oc = ot * 16 + kg * 4 + r;
      const int pxx = xbase + t * 16 + m;
      const int px = y * kW + pxx;
      const size_t off = (size_t)oc * kHW + px;
      const float q = acc[t][r] + bq[oc];
      const float zg = 1.f / (1.f + expf(-zpre[off]));
      const float hn = (1.f - zg) * hbuf[off] + zg * tanhf(q);
      hbuf[off] = hn;
      const int ppix = (y + 1) * kWp2 + pxx + 1;
      hT[(size_t)ppix * kCHh + oc] = f2b(hn);
    }
}

// conv_h: 2-way split-K (4 chunks); relu + spatial-sum -> feat atomics. grid (4, 96)
__global__ __launch_bounds__(256) void conv_h_k(const unsigned short* __restrict__ hT,
                                                const unsigned short* __restrict__ P,
                                                const float* __restrict__ bh,
                                                float* __restrict__ feat) {
  __shared__ f32x4 red[2][2][64];
  const int tid = threadIdx.x;
  const int wv = tid >> 6, lane = tid & 63;
  const int p = wv >> 1, half = wv & 1;
  const int y = blockIdx.y >> 1, xbase = (blockIdx.y & 1) * 32;
  const int ot = blockIdx.x * 2 + p;
  f32x4 acc[2] = {{0.f,0.f,0.f,0.f},{0.f,0.f,0.f,0.f}};
  if (half == 0) conv_core32<0, 2, 4, 4>(hT, hT, P, y, xbase, ot, lane, acc);
  else           conv_core32<2, 4, 4, 4>(hT, hT, P, y, xbase, ot, lane, acc);
  if (half == 1) {
    red[p][0][lane] = acc[0];
    red[p][1][lane] = acc[1];
  }
  __syncthreads();
  if (half != 0) return;
  acc[0] += red[p][0][lane];
  acc[1] += red[p][1][lane];
  const int m = lane & 15, kg = lane >> 4;
#pragma unroll
  for (int r = 0; r < 4; ++r) {
    const int oc = ot * 16 + kg * 4 + r;
    const float bv = bh[oc];
    float v = fmaxf(acc[0][r] + bv, 0.f) + fmaxf(acc[1][r] + bv, 0.f);
    v += __shfl_xor(v, 1, 64);
    v += __shfl_xor(v, 2, 64);
    v += __shfl_xor(v, 4, 64);
    v += __shfl_xor(v, 8, 64);
    if (m == 0) atomicAdd(&feat[oc], v);
  }
}

// ---------------- FC + pose update; zeroes feat & conf; refreshes samp ----------------
__global__ void pose_update_k(float* __restrict__ feat, float* __restrict__ conf,
                              const float* __restrict__ Wfc,
                              const float* __restrict__ bfc, float* __restrict__ pose,
                              float* __restrict__ samp, float* __restrict__ out) {
  __shared__ float s_d[7];
  __shared__ float s_pose[7];
  int t = threadIdx.x;
  if (t < 7) {
    float s = 0.f;
    const float inv = 1.f / (float)kHW;
    for (int k = 0; k < kHidden; ++k) s += (feat[k] * inv) * Wfc[k * 7 + t];
    s_d[t] = 0.01f * (s + bfc[t]);
  }
  __syncthreads();
  if (t < kHidden) feat[t] = 0.f;
  if (t < 64) conf[t] = 0.f;
  if (t == 0) {
    float qc[4] = {pose[0], pose[1], pose[2], pose[3]};
    float tc[3] = {pose[4], pose[5], pose[6]};
    float dq[4] = {1.f + s_d[0], s_d[1], s_d[2], s_d[3]};
    float inv = 1.f / sqrtf(dq[0]*dq[0] + dq[1]*dq[1] + dq[2]*dq[2] + dq[3]*dq[3]);
    dq[0] *= inv; dq[1] *= inv; dq[2] *= inv; dq[3] *= inv;
    float dv[3] = {s_d[4], s_d[5], s_d[6]};
    float rv[3];
    d_qapply(qc, dv, rv);
    float tn[3] = {tc[0] + rv[0], tc[1] + rv[1], tc[2] + rv[2]};
    float qn[4];
    d_qmul(qc, dq, qn);
    float inv2 = 1.f / sqrtf(qn[0]*qn[0] + qn[1]*qn[1] + qn[2]*qn[2] + qn[3]*qn[3]);
    qn[0] *= inv2; qn[1] *= inv2; qn[2] *= inv2; qn[3] *= inv2;
    s_pose[0] = qn[0]; s_pose[1] = qn[1]; s_pose[2] = qn[2]; s_pose[3] = qn[3];
    s_pose[4] = tn[0]; s_pose[5] = tn[1]; s_pose[6] = tn[2];
    pose[0] = qn[0]; pose[1] = qn[1]; pose[2] = qn[2]; pose[3] = qn[3];
    pose[4] = tn[0]; pose[5] = tn[1]; pose[6] = tn[2];
    out[0] = qn[0]; out[1] = qn[1]; out[2] = qn[2]; out[3] = qn[3];
    out[4] = tn[0]; out[5] = tn[1]; out[6] = tn[2];
  }
  __syncthreads();
  if (t < kNS) sample_Rt(t, s_pose, samp + t * 12);
}

// ---------------- launch ----------------
extern "C" void kernel_launch(void* const* d_in, const int* in_sizes, int n_in,
                              void* d_out, int out_size, void* d_ws, size_t ws_size,
                              hipStream_t stream) {
  const float* frgb  = (const float*)d_in[0];
  const float* fdep  = (const float*)d_in[1];
  const float* depth = (const float*)d_in[2];
  const float* ctx   = (const float*)d_in[3];
  const float* intr  = (const float*)d_in[4];
  const float* Wz = (const float*)d_in[5];
  const float* bz = (const float*)d_in[6];
  const float* Wr = (const float*)d_in[7];
  const float* br = (const float*)d_in[8];
  const float* Wq = (const float*)d_in[9];
  const float* bq = (const float*)d_in[10];
  const float* Wh = (const float*)d_in[11];
  const float* bh = (const float*)d_in[12];
  const float* Wfc = (const float*)d_in[13];
  const float* bfc = (const float*)d_in[14];
  float* outp = (float*)d_out;

  float* ws = (float*)d_ws;
  unsigned short* us = (unsigned short*)d_ws;
  unsigned short* corr0 = us + U_CORR0;
  unsigned short* corr1 = us + U_CORR1;
  unsigned short* corr2 = us + U_CORR2;
  unsigned short* corr3 = us + U_CORR3;
  float* X    = ws + F_X;
  float* hbuf = ws + F_H;
  float* zpre = ws + F_ZPRE;
  unsigned short* fcT = us + U_FCT;
  unsigned short* hT  = us + U_HT;
  unsigned short* rhT = us + U_RHT;
  unsigned short* Pzr = us + U_PZR;
  unsigned short* Pq  = us + U_PQ;
  unsigned short* Ph  = us + U_PH;
  float* bzr  = ws + F_BZR;
  float* conf = ws + F_CONF;
  float* pose = ws + F_POSE;
  float* feat = ws + F_FEAT;
  float* samp = ws + F_SAMP;
  unsigned short* fdT  = us + U_FDT;
  unsigned short* qT   = us + U_QT;
  unsigned short* Sbox = us + U_SBOX;  // overlays fdT/qT after setup

  init_k<<<1536, 256, 0, stream>>>(ctx, bz, br, depth, intr, hbuf,
                                   (unsigned int*)fcT, fcT, bzr, X, conf, feat,
                                   pose, samp);
  initctx_k<<<768, 256, 0, stream>>>(ctx, fcT);
  pack_k<<<(16 * 9 * 17 * 64 + 255) / 256, 256, 0, stream>>>(Wz, Wr, 128, 256, 17,
                                                             kGin, Pzr);
  pack_k<<<(8 * 9 * 17 * 64 + 255) / 256, 256, 0, stream>>>(Wq, Wq, 128, 128, 17,
                                                            kGin, Pq);
  pack_k<<<(8 * 9 * 4 * 64 + 255) / 256, 256, 0, stream>>>(Wh, Wh, 128, 128, 4,
                                                           kHidden, Ph);
  t_bf16_k<<<dim3(48, 4), 256, 0, stream>>>(fdep, fdT);
  t_bf16_k<<<dim3(48, 4), 256, 0, stream>>>(frgb, qT);
  corr_mfma_k<<<dim3(24, 24), 256, 0, stream>>>(fdT, qT, corr0);
  boxbuild_k<<<kHW, 256, 0, stream>>>(corr0, corr1, corr2, corr3, Sbox);

  for (int it = 0; it < kIters; ++it) {
    conf_k<<<444, 256, 0, stream>>>(Sbox, X, samp, intr, conf);
    fused_k<<<kHW, 256, 0, stream>>>(corr0, corr1, corr2, corr3, X, samp, intr,
                                     conf, fcT);
    conv_zr_k<<<dim3(16, 96), 256, 0, stream>>>(hT, fcT, Pzr, bzr, zpre, hbuf, rhT);
    conv_q_k<<<dim3(8, 96), 256, 0, stream>>>(rhT, fcT, hT, Pq, bq, zpre, hbuf);
    conv_h_k<<<dim3(4, 96), 256, 0, stream>>>(hT, Ph, bh, feat);
    pose_update_k<<<1, 128, 0, stream>>>(feat, conf, Wfc, bfc, pose, samp, outp);
  }
}